// Round 3
// baseline (6936.524 us; speedup 1.0000x reference)
//
#include <hip/hip_runtime.h>
#include <hip/hip_bf16.h>

#define TT 64
#define BB 256
#define DD 300
#define HH 512

typedef __attribute__((ext_vector_type(8))) short short8;
typedef __attribute__((ext_vector_type(4))) short s16x4;
typedef __attribute__((ext_vector_type(4))) float f32x4;

static __device__ __forceinline__ short f2bf(float x) {
    __hip_bfloat16 h = __float2bfloat16(x);
    return *reinterpret_cast<short*>(&h);
}

// XOR-swizzle (T2-style) for [16][*] bf16 LDS tiles whose row stride is a
// multiple of 128B: flips byte bits 4-6 by (row&7) so the 16 rows of an
// MFMA A-fragment ds_read_b128 land on 8 distinct 16B slots (2-way = free).
static __device__ __forceinline__ int swz(int row, int byteoff) {
    return byteoff ^ ((row & 7) << 4);
}

// ---------------------------------------------------------------------------
// k_pack: one-time repack of all weights into MFMA-B fragment-major bf16.
//   frag layout: P[((fN*KB + kb)*64 + lane)*8 + j] = W[k][n]
//     n = fN*16 + (lane&15),  k = kb*32 + (lane>>4)*8 + j
//   The SAME (lane,j)->k map is used for A fragments, so any internal HW
//   k-permutation cancels; only the HW-verified C/D layout is load-bearing.
//   Wzr: 64 fN x 16 kb (cols 0-511 Wz, 512-1023 Wr)
//   Wo : 32 fN x 16 kb
//   Up : 96 fN x 10 kb (cols: Uz|Ur|Uo), K padded 300->320 with zeros
// grid 624 x 256
// ---------------------------------------------------------------------------
__global__ __launch_bounds__(256) void k_pack(
    const float* __restrict__ Wz, const float* __restrict__ Wr,
    const float* __restrict__ Wo,
    const float* __restrict__ Uz, const float* __restrict__ Ur,
    const float* __restrict__ Uo,
    short* __restrict__ Wzr_p, short* __restrict__ Wo_p, short* __restrict__ Up)
{
    int g = blockIdx.x * 256 + threadIdx.x;   // 0..159743
    short8 v;
    if (g < 65536) {                           // Wzr
        int lane = g & 63, fkb = g >> 6;
        int kb = fkb & 15, fN = fkb >> 4;
        int n = fN * 16 + (lane & 15);
        int k0 = kb * 32 + ((lane >> 4) << 3);
        const float* W = (n < HH) ? Wz : Wr;
        int nn = (n < HH) ? n : n - HH;
        #pragma unroll
        for (int j = 0; j < 8; ++j) v[j] = f2bf(W[(k0 + j) * HH + nn]);
        *(short8*)&Wzr_p[(long)g * 8] = v;
    } else if (g < 98304) {                    // Wo
        int idx = g - 65536;
        int lane = idx & 63, fkb = idx >> 6;
        int kb = fkb & 15, fN = fkb >> 4;
        int n = fN * 16 + (lane & 15);
        int k0 = kb * 32 + ((lane >> 4) << 3);
        #pragma unroll
        for (int j = 0; j < 8; ++j) v[j] = f2bf(Wo[(k0 + j) * HH + n]);
        *(short8*)&Wo_p[(long)idx * 8] = v;
    } else {                                   // U (zero-padded K 300->320)
        int idx = g - 98304;                   // 0..61439
        int lane = idx & 63, fkb = idx >> 6;   // fkb 0..959
        int kb = fkb % 10, fN = fkb / 10;      // kb 0..9, fN 0..95
        int n = fN * 16 + (lane & 15);         // 0..1535
        int k0 = kb * 32 + ((lane >> 4) << 3);
        const float* Us; int nn;
        if (n < HH)          { Us = Uz; nn = n; }
        else if (n < 2 * HH) { Us = Ur; nn = n - HH; }
        else                 { Us = Uo; nn = n - 2 * HH; }
        #pragma unroll
        for (int j = 0; j < 8; ++j) {
            int k = k0 + j;
            v[j] = (k < DD) ? f2bf(Us[k * HH + nn]) : (short)0;
        }
        *(short8*)&Up[(long)idx * 8] = v;
    }
}

// ---------------------------------------------------------------------------
// k_gru: persistent fused recurrence. 32 wgs x 512 thr (8 waves).
// wg owns rows m0=wg*16 (row = s*256+b). h lives in LDS for all 64 steps:
// zero global traffic for state; per step only packed-W/U reads (L2) and the
// 16 emb rows for x_t (L3). Per step:
//   stage: As[16][320] = bf16(emb[tok(b,t)]), swizzled, zero-padded
//   phase A (N=1024): acc = x@U(10kb) + h@Wzr(16kb); sigmoid ->
//       cols<512: z32 (f32 LDS);  cols>=512: rh = r*h -> rhb (bf16 swz LDS)
//   phase B (N=512):  acc = x@Uo(10kb) + rh@Wo(16kb); o=tanh;
//       h' = z*h + (1-z)*o -> h32 (f32) + hb (bf16 swz)
// Wave n-split: A: wave w -> nfrags 8w..8w+7; B: 4w..4w+3.
// LDS: hb 16K | rhb 16K | As 10K | h32 32K | z32 32K | stok 4K = 110.0 KiB
// ---------------------------------------------------------------------------
__global__ __launch_bounds__(512) void k_gru(
    const int* __restrict__ tok1, const int* __restrict__ tok2,
    const float* __restrict__ emb,
    const short* __restrict__ Wzr_p, const short* __restrict__ Wo_p,
    const short* __restrict__ Up,
    const float* __restrict__ bz, const float* __restrict__ br,
    const float* __restrict__ bo,
    float* __restrict__ h_final)
{
    extern __shared__ char smem[];
    short* hb  = (short*)(smem);            // [16][512] bf16, swizzled
    short* rhb = (short*)(smem + 16384);    // [16][512] bf16, swizzled
    short* As  = (short*)(smem + 32768);    // [16][320] bf16, swizzled
    float* h32 = (float*)(smem + 43008);    // [16][512] f32
    float* z32 = (float*)(smem + 75776);    // [16][512] f32
    int*  stok = (int*)  (smem + 108544);   // [16][64]

    const int tid  = threadIdx.x;
    const int lane = tid & 63;
    const int w    = tid >> 6;              // wave 0..7
    const int r16  = lane & 15;             // MFMA frag row/col within 16
    const int kg   = lane >> 4;             // k-group 0..3
    const int wg   = blockIdx.x;            // 0..31
    const int m0   = wg * 16;
    const int s    = m0 >> 8;               // 0:tokens1, 1:tokens2
    const int b0   = m0 & 255;
    const int* tokens = s ? tok2 : tok1;

    // init: zero h state, stage this wg's token rows
    for (int i = tid; i < 1024; i += 512) ((f32x4*)hb)[i]  = (f32x4){0,0,0,0};
    for (int i = tid; i < 2048; i += 512) ((f32x4*)h32)[i] = (f32x4){0,0,0,0};
    for (int i = tid; i < 1024; i += 512)
        stok[i] = tokens[(b0 + (i >> 6)) * TT + (i & 63)];
    __syncthreads();

    for (int t = 0; t < TT; ++t) {
        // ---- stage As = bf16(emb rows for step t), swizzled, pad k>=300 ----
        {
            int row = tid >> 5;             // 0..15
            int seg = tid & 31;             // 0..31
            const float* erow = emb + (long)stok[row * TT + t] * DD;
            #pragma unroll
            for (int q = 0; q < 3; ++q) {
                int col = q * 128 + 4 * seg;            // q2 covers 256..316
                if (q < 2 || seg < 16) {
                    float4 v = {0.f, 0.f, 0.f, 0.f};
                    if (col < 297) v = *(const float4*)(erow + col);
                    s16x4 o;
                    o[0] = f2bf(v.x); o[1] = f2bf(v.y);
                    o[2] = f2bf(v.z); o[3] = f2bf(v.w);
                    *(s16x4*)((char*)As + row * 640 + swz(row, col * 2)) = o;
                }
            }
        }
        __syncthreads();

        // ---- phase A: pre[16][1024] = x@[Uz|Ur] + h@[Wz|Wr] ----
        {
            f32x4 acc[8];
            #pragma unroll
            for (int i = 0; i < 8; ++i) acc[i] = (f32x4){0,0,0,0};
            #pragma unroll
            for (int kb = 0; kb < 10; ++kb) {           // x@U part (K=320)
                short8 au = *(const short8*)((const char*)As + r16 * 640
                              + swz(r16, (kb * 32 + kg * 8) * 2));
                const short* bp = Up + ((8 * w * 10 + kb) * 64 + lane) * 8;
                #pragma unroll
                for (int i = 0; i < 8; ++i) {
                    short8 bv = *(const short8*)(bp + i * 5120); // 10*64*8
                    acc[i] = __builtin_amdgcn_mfma_f32_16x16x32_bf16(au, bv, acc[i], 0, 0, 0);
                }
            }
            #pragma unroll
            for (int kb = 0; kb < 16; ++kb) {           // h@W part (K=512)
                short8 ah = *(const short8*)((const char*)hb + r16 * 1024
                              + swz(r16, (kb * 32 + kg * 8) * 2));
                const short* bp = Wzr_p + ((8 * w * 16 + kb) * 64 + lane) * 8;
                #pragma unroll
                for (int i = 0; i < 8; ++i) {
                    short8 bv = *(const short8*)(bp + i * 8192); // 16*64*8
                    acc[i] = __builtin_amdgcn_mfma_f32_16x16x32_bf16(ah, bv, acc[i], 0, 0, 0);
                }
            }
            // epilogue: sigmoid; z -> z32, r -> rh_b = bf16(r*h)
            #pragma unroll
            for (int i = 0; i < 8; ++i) {
                int col = (8 * w + i) * 16 + r16;       // 0..1023, block-uniform vs 512
                float bias = (col < HH) ? bz[col] : br[col - HH];
                #pragma unroll
                for (int r = 0; r < 4; ++r) {
                    int row = kg * 4 + r;               // C/D map: col=lane&15, row=(lane>>4)*4+reg
                    float g = 1.f / (1.f + __expf(-(acc[i][r] + bias)));
                    if (col < HH) {
                        z32[row * HH + col] = g;
                    } else {
                        int cl = col - HH;
                        float hv = h32[row * HH + cl];
                        *(short*)((char*)rhb + row * 1024 + swz(row, cl * 2)) = f2bf(g * hv);
                    }
                }
            }
        }
        __syncthreads();

        // ---- phase B: o = tanh(x@Uo + rh@Wo);  h' = z*h + (1-z)*o ----
        {
            f32x4 acc[4];
            #pragma unroll
            for (int i = 0; i < 4; ++i) acc[i] = (f32x4){0,0,0,0};
            #pragma unroll
            for (int kb = 0; kb < 10; ++kb) {           // x@Uo (nf 64..95)
                short8 au = *(const short8*)((const char*)As + r16 * 640
                              + swz(r16, (kb * 32 + kg * 8) * 2));
                const short* bp = Up + (((64 + 4 * w) * 10 + kb) * 64 + lane) * 8;
                #pragma unroll
                for (int i = 0; i < 4; ++i) {
                    short8 bv = *(const short8*)(bp + i * 5120);
                    acc[i] = __builtin_amdgcn_mfma_f32_16x16x32_bf16(au, bv, acc[i], 0, 0, 0);
                }
            }
            #pragma unroll
            for (int kb = 0; kb < 16; ++kb) {           // rh@Wo
                short8 ar = *(const short8*)((const char*)rhb + r16 * 1024
                              + swz(r16, (kb * 32 + kg * 8) * 2));
                const short* bp = Wo_p + ((4 * w * 16 + kb) * 64 + lane) * 8;
                #pragma unroll
                for (int i = 0; i < 4; ++i) {
                    short8 bv = *(const short8*)(bp + i * 8192);
                    acc[i] = __builtin_amdgcn_mfma_f32_16x16x32_bf16(ar, bv, acc[i], 0, 0, 0);
                }
            }
            #pragma unroll
            for (int i = 0; i < 4; ++i) {
                int col = (4 * w + i) * 16 + r16;       // 0..511
                float bias = bo[col];
                #pragma unroll
                for (int r = 0; r < 4; ++r) {
                    int row = kg * 4 + r;
                    float pre = acc[i][r] + bias;
                    float e = __expf(2.f * pre);        // tanh, inf-safe
                    float o = 1.f - 2.f / (e + 1.f);
                    float z  = z32[row * HH + col];
                    float hv = h32[row * HH + col];
                    float hn = z * hv + (1.f - z) * o;
                    h32[row * HH + col] = hn;
                    *(short*)((char*)hb + row * 1024 + swz(row, col * 2)) = f2bf(hn);
                }
            }
        }
        __syncthreads();
    }

    // ---- write final h (f32) to global ----
    {
        const f32x4* src = (const f32x4*)h32;
        f32x4* dst = (f32x4*)(h_final + (long)m0 * HH);
        for (int i = tid; i < 2048; i += 512) dst[i] = src[i];
    }
}

// ---------------------------------------------------------------------------
// Head: v = relu([h1, h2, (h1-h2)^2, h1*h2]);  out = v @ U + b.  grid 256.
// ---------------------------------------------------------------------------
__global__ __launch_bounds__(256) void k_head(
    const float* __restrict__ h, const float* __restrict__ U,
    const float* __restrict__ bias, float* __restrict__ out)
{
    const int b = blockIdx.x, tid = threadIdx.x;
    const float* h1 = h + b * HH;
    const float* h2 = h + (BB + b) * HH;
    float a0 = 0.f, a1 = 0.f;
    #pragma unroll
    for (int l = 0; l < 8; ++l) {
        int i = tid + l * 256;        // [0,2048)
        int seg = i >> 9, off = i & 511;
        float v;
        if (seg == 0)      v = fmaxf(h1[off], 0.f);
        else if (seg == 1) v = fmaxf(h2[off], 0.f);
        else if (seg == 2) { float d = h1[off] - h2[off]; v = d * d; }
        else               v = fmaxf(h1[off] * h2[off], 0.f);
        a0 += v * U[i * 2];
        a1 += v * U[i * 2 + 1];
    }
    __shared__ float red0[256];
    __shared__ float red1[256];
    red0[tid] = a0; red1[tid] = a1;
    __syncthreads();
    for (int sft = 128; sft > 0; sft >>= 1) {
        if (tid < sft) { red0[tid] += red0[tid + sft]; red1[tid] += red1[tid + sft]; }
        __syncthreads();
    }
    if (tid == 0) {
        out[b * 2]     = red0[0] + bias[0];
        out[b * 2 + 1] = red1[0] + bias[1];
    }
}

// ---------------------------------------------------------------------------
extern "C" void kernel_launch(void* const* d_in, const int* in_sizes, int n_in,
                              void* d_out, int out_size, void* d_ws, size_t ws_size,
                              hipStream_t stream)
{
    const int*   tok1 = (const int*)  d_in[0];
    const int*   tok2 = (const int*)  d_in[1];
    const float* emb  = (const float*)d_in[2];
    const float* Uz   = (const float*)d_in[3];
    const float* Ur   = (const float*)d_in[4];
    const float* Uo   = (const float*)d_in[5];
    const float* Wz   = (const float*)d_in[6];
    const float* Wr   = (const float*)d_in[7];
    const float* Wo   = (const float*)d_in[8];
    const float* bz   = (const float*)d_in[9];
    const float* br   = (const float*)d_in[10];
    const float* bo   = (const float*)d_in[11];
    const float* U    = (const float*)d_in[12];
    const float* bb   = (const float*)d_in[13];
    float* out = (float*)d_out;

    // workspace: packed weights (~2.5 MiB) + final h (1 MiB). No 96MB xU.
    char* ws = (char*)d_ws;
    short* Wzr_p = (short*)ws;                         // 524288 shorts
    short* Wo_p  = Wzr_p + 524288;                     // 262144 shorts
    short* Up    = Wo_p  + 262144;                     // 491520 shorts
    float* h_final = (float*)(ws + (size_t)(524288 + 262144 + 491520) * 2);

    // opt-in for 110KB dynamic LDS (no-op if not required on ROCm)
    static bool attr_set = false;
    if (!attr_set) {
        (void)hipFuncSetAttribute((const void*)k_gru,
                                  hipFuncAttributeMaxDynamicSharedMemorySize, 112640);
        attr_set = true;
    }

    dim3 blk(256);
    k_pack<<<dim3(624), blk, 0, stream>>>(Wz, Wr, Wo, Uz, Ur, Uo, Wzr_p, Wo_p, Up);
    k_gru<<<dim3(32), dim3(512), 112640, stream>>>(
        tok1, tok2, emb, Wzr_p, Wo_p, Up, bz, br, bo, h_final);
    k_head<<<dim3(256), blk, 0, stream>>>(h_final, U, bb, out);
}

// Round 5
// 1345.118 us; speedup vs baseline: 5.1568x; 5.1568x over previous
//
#include <hip/hip_runtime.h>
#include <hip/hip_bf16.h>

#define TT 64
#define BB 256
#define DD 300
#define HH 512

typedef __attribute__((ext_vector_type(8))) short short8;
typedef __attribute__((ext_vector_type(4))) short s16x4;
typedef __attribute__((ext_vector_type(4))) float f32x4;

static __device__ __forceinline__ short f2bf(float x) {
    __hip_bfloat16 h = __float2bfloat16(x);
    return *reinterpret_cast<short*>(&h);
}
// XOR-swizzle for [16][*] bf16 LDS tiles with 128B-multiple row stride:
// spreads the 16 same-column A-fragment rows across 8 16B slots (2-way = free).
static __device__ __forceinline__ int swz(int row, int byteoff) {
    return byteoff ^ ((row & 7) << 4);
}

// ---------------------------------------------------------------------------
// k_pack (unchanged, proven r3): weights -> MFMA-B fragment-major bf16.
//   P[((fN*KB + kb)*64 + lane)*8 + j] = W[k][n],
//   n = fN*16 + (lane&15), k = kb*32 + (lane>>4)*8 + j
// Wzr: fN 0..63 (z then r), KB=16. Wo: fN 0..31, KB=16. Up: fN 0..95
// (Uz|Ur|Uo), KB=10, K zero-padded 300->320.   grid 624 x 256
// ---------------------------------------------------------------------------
__global__ __launch_bounds__(256) void k_pack(
    const float* __restrict__ Wz, const float* __restrict__ Wr,
    const float* __restrict__ Wo,
    const float* __restrict__ Uz, const float* __restrict__ Ur,
    const float* __restrict__ Uo,
    short* __restrict__ Wzr_p, short* __restrict__ Wo_p, short* __restrict__ Up)
{
    int g = blockIdx.x * 256 + threadIdx.x;   // 0..159743
    short8 v;
    if (g < 65536) {                           // Wzr
        int lane = g & 63, fkb = g >> 6;
        int kb = fkb & 15, fN = fkb >> 4;
        int n = fN * 16 + (lane & 15);
        int k0 = kb * 32 + ((lane >> 4) << 3);
        const float* W = (n < HH) ? Wz : Wr;
        int nn = (n < HH) ? n : n - HH;
        #pragma unroll
        for (int j = 0; j < 8; ++j) v[j] = f2bf(W[(k0 + j) * HH + nn]);
        *(short8*)&Wzr_p[(long)g * 8] = v;
    } else if (g < 98304) {                    // Wo
        int idx = g - 65536;
        int lane = idx & 63, fkb = idx >> 6;
        int kb = fkb & 15, fN = fkb >> 4;
        int n = fN * 16 + (lane & 15);
        int k0 = kb * 32 + ((lane >> 4) << 3);
        #pragma unroll
        for (int j = 0; j < 8; ++j) v[j] = f2bf(Wo[(k0 + j) * HH + n]);
        *(short8*)&Wo_p[(long)idx * 8] = v;
    } else {                                   // U (zero-padded K 300->320)
        int idx = g - 98304;                   // 0..61439
        int lane = idx & 63, fkb = idx >> 6;   // fkb 0..959
        int kb = fkb % 10, fN = fkb / 10;      // kb 0..9, fN 0..95
        int n = fN * 16 + (lane & 15);
        int k0 = kb * 32 + ((lane >> 4) << 3);
        const float* Us; int nn;
        if (n < HH)          { Us = Uz; nn = n; }
        else if (n < 2 * HH) { Us = Ur; nn = n - HH; }
        else                 { Us = Uo; nn = n - 2 * HH; }
        #pragma unroll
        for (int j = 0; j < 8; ++j) {
            int k = k0 + j;
            v[j] = (k < DD) ? f2bf(Us[k * HH + nn]) : (short)0;
        }
        *(short8*)&Up[(long)idx * 8] = v;
    }
}

// ---------------------------------------------------------------------------
// Inter-workgroup epoch barrier (8-wg row-group, agent scope, directional
// fences). __syncthreads drains vmcnt before s_barrier, so all wg stores are
// in L2 before thread0's release fence (wbl2) publishes them; acquire fence
// (inv) by thread0 precedes the post-barrier loads of every wave (L1 is
// per-CU shared; L2 per-XCD).
// ---------------------------------------------------------------------------
static __device__ __forceinline__ void bar_arrive(int* c) {
    __syncthreads();
    if (threadIdx.x == 0) {
        __builtin_amdgcn_fence(__ATOMIC_RELEASE, "agent");
        __hip_atomic_fetch_add(c, 1, __ATOMIC_RELAXED, __HIP_MEMORY_SCOPE_AGENT);
    }
}
static __device__ __forceinline__ void bar_wait(int* c, int tgt) {
    if (threadIdx.x == 0) {
        int it = 0;
        while (__hip_atomic_load(c, __ATOMIC_RELAXED, __HIP_MEMORY_SCOPE_AGENT) < tgt
               && it < 262144) { ++it; __builtin_amdgcn_s_sleep(2); }
        __builtin_amdgcn_fence(__ATOMIC_ACQUIRE, "agent");
    }
    __syncthreads();
}

// ---------------------------------------------------------------------------
// k_gru: 256 wgs (32 row-tiles x 8 col-groups) x 256 thr (4 waves), 1 wg/CU.
// XCD-swizzled so each row-group's 8 wgs share one XCD (L2-local exchange).
// Per wg: rows rt*16..+16, output col-slice cg*64..+64 of each gate.
// Resident: Wz/Wr col-slice in LDS (128KB, once); Uz/Ur/Uo/Wo frags in VGPRs
// (46 frags = 184 VGPR, once); h f32 + z in VGPRs (C/D layout).
// Per step: x@U (h-independent, runs before barrier waits) + h@W from
// exchanged bf16 h (hb_g) + rh@Wo from exchanged rh (rh_g). 2 barriers/step.
// LDS: Wlds 128K | Ab 16K (hb/rh shared) | As 10K = 154 KiB
// ---------------------------------------------------------------------------
__global__ __launch_bounds__(256, 1) void k_gru(
    const int* __restrict__ tok1, const int* __restrict__ tok2,
    const float* __restrict__ emb,
    const short* __restrict__ Wzr_p, const short* __restrict__ Wo_p,
    const short* __restrict__ Up,
    const float* __restrict__ bz, const float* __restrict__ br,
    const float* __restrict__ bo,
    short* __restrict__ rh_g, short* __restrict__ hb_g,
    int* __restrict__ ctrs,
    float* __restrict__ h_final)
{
    extern __shared__ char smem[];
    short* Wlds = (short*)smem;              // [2][4fN][16kb][64][8] = 131072 B
    short* Ab   = (short*)(smem + 131072);   // [16][512] bf16 swz = 16384 B
    short* As   = (short*)(smem + 147456);   // [16][320] bf16 swz = 10240 B

    const int tid  = threadIdx.x;
    const int lane = tid & 63;
    const int w    = tid >> 6;               // wave 0..3
    const int r16  = lane & 15;
    const int kg   = lane >> 4;
    const int wg   = blockIdx.x;
    // XCD swizzle: round-robin dispatch puts wg on XCD wg%8; this mapping
    // gives row-group rt all 8 of its wgs on XCD rt>>2 (4 rgs/XCD = 32 CUs).
    const int rt   = (wg & 7) * 4 + ((wg >> 3) & 3);   // row-tile 0..31
    const int cg   = wg >> 5;                          // col-group 0..7
    const int ncol = cg * 64 + w * 16 + r16; // this lane's output column
    int* bar1 = ctrs + rt * 32;              // rh-ready
    int* bar2 = ctrs + rt * 32 + 16;         // h-ready

    // ---- one-time: Wz/Wr slice -> LDS (fragment-major, verbatim copy) ----
    {
        const f32x4* gz = (const f32x4*)(Wzr_p + (size_t)cg * 32768);
        const f32x4* gr = (const f32x4*)(Wzr_p + (size_t)(262144 + cg * 32768));
        f32x4* dz = (f32x4*)Wlds;
        f32x4* dr = (f32x4*)(Wlds + 32768);
        for (int i = tid; i < 4096; i += 256) { dz[i] = gz[i]; dr[i] = gr[i]; }
    }
    // ---- one-time: U/Wo fragments -> registers (static-indexed arrays) ----
    short8 fUz[10], fUr[10], fUo[10], fWo[16];
    {
        const short8* up = (const short8*)Up;
        const short8* wo = (const short8*)Wo_p;
        int fz = cg * 4 + w, fr = 32 + cg * 4 + w, fo = 64 + cg * 4 + w;
        #pragma unroll
        for (int kb = 0; kb < 10; ++kb) {
            fUz[kb] = up[(size_t)(fz * 10 + kb) * 64 + lane];
            fUr[kb] = up[(size_t)(fr * 10 + kb) * 64 + lane];
            fUo[kb] = up[(size_t)(fo * 10 + kb) * 64 + lane];
        }
        #pragma unroll
        for (int kb = 0; kb < 16; ++kb)
            fWo[kb] = wo[(size_t)((cg * 4 + w) * 16 + kb) * 64 + lane];
    }
    const float bzv = bz[ncol], brv = br[ncol], bov = bo[ncol];

    // ---- one-time: zero-pad As cols 300..319 (never restaged) ----
    for (int i = tid; i < 160; i += 256) {
        int row = i / 10, j = i % 10;
        *(int*)((char*)As + row * 640 + swz(row, 600 + j * 4)) = 0;
    }
    __syncthreads();

    // ---- stage As(t=0): 16 gathered emb rows, f32 -> bf16, swizzled ----
    {
        int row = tid >> 4, sgt = tid & 15;
        int m = rt * 16 + row;
        const int* tk = (m >= BB) ? tok2 : tok1;
        const float* er = emb + (size_t)tk[(m & 255) * TT + 0] * DD;
        #pragma unroll
        for (int p = 0; p < 5; ++p) {
            int c = sgt * 4 + p * 64;
            if (c < DD) {
                float4 v = *(const float4*)(er + c);
                s16x4 o;
                o[0] = f2bf(v.x); o[1] = f2bf(v.y); o[2] = f2bf(v.z); o[3] = f2bf(v.w);
                *(s16x4*)((char*)As + row * 640 + swz(row, c * 2)) = o;
            }
        }
    }
    __syncthreads();

    float hreg[4] = {0.f, 0.f, 0.f, 0.f};   // h[row=kg*4+q][ncol], f32 master
    float zreg[4];

    for (int t = 0; t < TT; ++t) {
        // ================= phase A =================
        f32x4 zac = {0,0,0,0}, rac = {0,0,0,0};
        #pragma unroll
        for (int kb = 0; kb < 10; ++kb) {    // x@U (h-independent: pre-wait)
            short8 au = *(const short8*)((char*)As + r16 * 640
                          + swz(r16, kb * 64 + kg * 16));
            zac = __builtin_amdgcn_mfma_f32_16x16x32_bf16(au, fUz[kb], zac, 0, 0, 0);
            rac = __builtin_amdgcn_mfma_f32_16x16x32_bf16(au, fUr[kb], rac, 0, 0, 0);
        }
        if (t > 0) {
            bar_wait(bar2, 8 * t);           // h(t-1) slices ready
            for (int i = tid; i < 1024; i += 256) {   // stage hb -> Ab
                int row = i >> 6, c = i & 63;
                short8 v = ((const short8*)(hb_g + (size_t)rt * 8192))[row * 64 + c];
                *(short8*)((char*)Ab + row * 1024 + swz(row, c * 16)) = v;
            }
            __syncthreads();
            #pragma unroll
            for (int kb = 0; kb < 16; ++kb) {          // h@[Wz|Wr]
                short8 ah = *(const short8*)((char*)Ab + r16 * 1024
                              + swz(r16, kb * 64 + kg * 16));
                short8 wzf = *(const short8*)&Wlds[(w * 16 + kb) * 512 + lane * 8];
                short8 wrf = *(const short8*)&Wlds[32768 + (w * 16 + kb) * 512 + lane * 8];
                zac = __builtin_amdgcn_mfma_f32_16x16x32_bf16(ah, wzf, zac, 0, 0, 0);
                rac = __builtin_amdgcn_mfma_f32_16x16x32_bf16(ah, wrf, rac, 0, 0, 0);
            }
        }
        // epilogue A: z local; rh slice -> global exchange
        #pragma unroll
        for (int q = 0; q < 4; ++q) {
            zreg[q] = 1.f / (1.f + __expf(-(zac[q] + bzv)));
            float rg = 1.f / (1.f + __expf(-(rac[q] + brv)));
            if (t > 0)
                rh_g[(size_t)(rt * 16 + kg * 4 + q) * HH + ncol] = f2bf(rg * hreg[q]);
        }
        if (t > 0) bar_arrive(bar1);

        // ================= phase B =================
        f32x4 oac = {0,0,0,0};
        #pragma unroll
        for (int kb = 0; kb < 10; ++kb) {    // x@Uo (pre-wait)
            short8 au = *(const short8*)((char*)As + r16 * 640
                          + swz(r16, kb * 64 + kg * 16));
            oac = __builtin_amdgcn_mfma_f32_16x16x32_bf16(au, fUo[kb], oac, 0, 0, 0);
        }
        __syncthreads();                     // all As(t) reads complete
        if (t < TT - 1) {                    // stage As(t+1) into barrier shadow
            int row = tid >> 4, sgt = tid & 15;
            int m = rt * 16 + row;
            const int* tk = (m >= BB) ? tok2 : tok1;
            const float* er = emb + (size_t)tk[(m & 255) * TT + (t + 1)] * DD;
            #pragma unroll
            for (int p = 0; p < 5; ++p) {
                int c = sgt * 4 + p * 64;
                if (c < DD) {
                    float4 v = *(const float4*)(er + c);
                    s16x4 o;
                    o[0] = f2bf(v.x); o[1] = f2bf(v.y); o[2] = f2bf(v.z); o[3] = f2bf(v.w);
                    *(s16x4*)((char*)As + row * 640 + swz(row, c * 2)) = o;
                }
            }
        }
        if (t > 0) {
            bar_wait(bar1, 8 * t);           // rh(t) slices ready
            for (int i = tid; i < 1024; i += 256) {   // stage rh -> Ab
                int row = i >> 6, c = i & 63;
                short8 v = ((const short8*)(rh_g + (size_t)rt * 8192))[row * 64 + c];
                *(short8*)((char*)Ab + row * 1024 + swz(row, c * 16)) = v;
            }
            __syncthreads();
            #pragma unroll
            for (int kb = 0; kb < 16; ++kb) {          // rh@Wo
                short8 ar = *(const short8*)((char*)Ab + r16 * 1024
                              + swz(r16, kb * 64 + kg * 16));
                oac = __builtin_amdgcn_mfma_f32_16x16x32_bf16(ar, fWo[kb], oac, 0, 0, 0);
            }
        } else {
            __syncthreads();                 // As(1) visible (no bar1 at t=0)
        }
        // epilogue B: h' = z*h + (1-z)*tanh(.); keep f32, exchange bf16
        #pragma unroll
        for (int q = 0; q < 4; ++q) {
            float pre = oac[q] + bov;
            float e = __expf(2.f * pre);     // tanh, inf-safe
            float o = 1.f - 2.f / (e + 1.f);
            float hn = zreg[q] * hreg[q] + (1.f - zreg[q]) * o;
            hreg[q] = hn;
            hb_g[(size_t)(rt * 16 + kg * 4 + q) * HH + ncol] = f2bf(hn);
        }
        bar_arrive(bar2);
    }

    // ---- final h (f32) ----
    #pragma unroll
    for (int q = 0; q < 4; ++q)
        h_final[(size_t)(rt * 16 + kg * 4 + q) * HH + ncol] = hreg[q];
}

// ---------------------------------------------------------------------------
// Head: v = relu([h1, h2, (h1-h2)^2, h1*h2]);  out = v @ U + b.  grid 256.
// ---------------------------------------------------------------------------
__global__ __launch_bounds__(256) void k_head(
    const float* __restrict__ h, const float* __restrict__ U,
    const float* __restrict__ bias, float* __restrict__ out)
{
    const int b = blockIdx.x, tid = threadIdx.x;
    const float* h1 = h + b * HH;
    const float* h2 = h + (BB + b) * HH;
    float a0 = 0.f, a1 = 0.f;
    #pragma unroll
    for (int l = 0; l < 8; ++l) {
        int i = tid + l * 256;        // [0,2048)
        int seg = i >> 9, off = i & 511;
        float v;
        if (seg == 0)      v = fmaxf(h1[off], 0.f);
        else if (seg == 1) v = fmaxf(h2[off], 0.f);
        else if (seg == 2) { float d = h1[off] - h2[off]; v = d * d; }
        else               v = fmaxf(h1[off] * h2[off], 0.f);
        a0 += v * U[i * 2];
        a1 += v * U[i * 2 + 1];
    }
    __shared__ float red0[256];
    __shared__ float red1[256];
    red0[tid] = a0; red1[tid] = a1;
    __syncthreads();
    for (int sft = 128; sft > 0; sft >>= 1) {
        if (tid < sft) { red0[tid] += red0[tid + sft]; red1[tid] += red1[tid + sft]; }
        __syncthreads();
    }
    if (tid == 0) {
        out[b * 2]     = red0[0] + bias[0];
        out[b * 2 + 1] = red1[0] + bias[1];
    }
}

// ---------------------------------------------------------------------------
extern "C" void kernel_launch(void* const* d_in, const int* in_sizes, int n_in,
                              void* d_out, int out_size, void* d_ws, size_t ws_size,
                              hipStream_t stream)
{
    (void)in_sizes; (void)n_in; (void)out_size; (void)ws_size;
    const int*   tok1 = (const int*)  d_in[0];
    const int*   tok2 = (const int*)  d_in[1];
    const float* emb  = (const float*)d_in[2];
    const float* Uz   = (const float*)d_in[3];
    const float* Ur   = (const float*)d_in[4];
    const float* Uo   = (const float*)d_in[5];
    const float* Wz   = (const float*)d_in[6];
    const float* Wr   = (const float*)d_in[7];
    const float* Wo   = (const float*)d_in[8];
    const float* bz   = (const float*)d_in[9];
    const float* br   = (const float*)d_in[10];
    const float* bo   = (const float*)d_in[11];
    const float* U    = (const float*)d_in[12];
    const float* bb   = (const float*)d_in[13];
    float* out = (float*)d_out;

    // ws: Wzr_p 1MB | Wo_p 0.5MB | Up 0.96MB | rh_g 0.5MB | hb_g 0.5MB |
    //     h_final 1MB | ctrs 4KB   (total ~4.5MB)
    char* ws = (char*)d_ws;
    short* Wzr_p   = (short*)ws;
    short* Wo_p    = Wzr_p + 524288;
    short* Up      = Wo_p + 262144;
    short* rh_g    = Up + 491520;
    short* hb_g    = rh_g + 262144;
    float* h_final = (float*)(hb_g + 262144);
    int*   ctrs    = (int*)(h_final + 262144);

    static bool attr_set = false;
    if (!attr_set) {
        (void)hipFuncSetAttribute((const void*)k_gru,
                                  hipFuncAttributeMaxDynamicSharedMemorySize, 157696);
        attr_set = true;
    }

    hipMemsetAsync(ctrs, 0, 32 * 32 * sizeof(int), stream);
    dim3 blk(256);
    k_pack<<<dim3(624), blk, 0, stream>>>(Wz, Wr, Wo, Uz, Ur, Uo, Wzr_p, Wo_p, Up);
    k_gru<<<dim3(256), blk, 157696, stream>>>(
        tok1, tok2, emb, Wzr_p, Wo_p, Up, bz, br, bo, rh_g, hb_g, ctrs, h_final);
    k_head<<<dim3(256), blk, 0, stream>>>(h_final, U, bb, out);
}

// Round 7
// 799.555 us; speedup vs baseline: 8.6755x; 1.6823x over previous
//
#include <hip/hip_runtime.h>
#include <hip/hip_bf16.h>

#define TT 64
#define BB 256
#define DD 300
#define HH 512

typedef __attribute__((ext_vector_type(8))) short short8;
typedef __attribute__((ext_vector_type(4))) short s16x4;
typedef __attribute__((ext_vector_type(4))) float f32x4;
typedef unsigned long long ull;

static __device__ __forceinline__ short f2bf(float x) {
    __hip_bfloat16 h = __float2bfloat16(x);
    return *reinterpret_cast<short*>(&h);
}
// XOR-swizzle for [16][*] bf16 LDS tiles with 128B-multiple row stride:
// spreads the 16 same-column A-fragment rows across 8 16B slots (2-way = free).
static __device__ __forceinline__ int swz(int row, int byteoff) {
    return byteoff ^ ((row & 7) << 4);
}

// ---------------------------------------------------------------------------
// k_pack (unchanged, proven r3/r5): weights -> MFMA-B fragment-major bf16.
//   P[((fN*KB + kb)*64 + lane)*8 + j] = W[k][n],
//   n = fN*16 + (lane&15), k = kb*32 + (lane>>4)*8 + j
// Wzr: fN 0..63 (z then r), KB=16. Wo: fN 0..31, KB=16. Up: fN 0..95
// (Uz|Ur|Uo), KB=10, K zero-padded 300->320.   grid 624 x 256
// ---------------------------------------------------------------------------
__global__ __launch_bounds__(256) void k_pack(
    const float* __restrict__ Wz, const float* __restrict__ Wr,
    const float* __restrict__ Wo,
    const float* __restrict__ Uz, const float* __restrict__ Ur,
    const float* __restrict__ Uo,
    short* __restrict__ Wzr_p, short* __restrict__ Wo_p, short* __restrict__ Up)
{
    int g = blockIdx.x * 256 + threadIdx.x;   // 0..159743
    short8 v;
    if (g < 65536) {                           // Wzr
        int lane = g & 63, fkb = g >> 6;
        int kb = fkb & 15, fN = fkb >> 4;
        int n = fN * 16 + (lane & 15);
        int k0 = kb * 32 + ((lane >> 4) << 3);
        const float* W = (n < HH) ? Wz : Wr;
        int nn = (n < HH) ? n : n - HH;
        #pragma unroll
        for (int j = 0; j < 8; ++j) v[j] = f2bf(W[(k0 + j) * HH + nn]);
        *(short8*)&Wzr_p[(long)g * 8] = v;
    } else if (g < 98304) {                    // Wo
        int idx = g - 65536;
        int lane = idx & 63, fkb = idx >> 6;
        int kb = fkb & 15, fN = fkb >> 4;
        int n = fN * 16 + (lane & 15);
        int k0 = kb * 32 + ((lane >> 4) << 3);
        #pragma unroll
        for (int j = 0; j < 8; ++j) v[j] = f2bf(Wo[(k0 + j) * HH + n]);
        *(short8*)&Wo_p[(long)idx * 8] = v;
    } else {                                   // U (zero-padded K 300->320)
        int idx = g - 98304;                   // 0..61439
        int lane = idx & 63, fkb = idx >> 6;   // fkb 0..959
        int kb = fkb % 10, fN = fkb / 10;      // kb 0..9, fN 0..95
        int n = fN * 16 + (lane & 15);
        int k0 = kb * 32 + ((lane >> 4) << 3);
        const float* Us; int nn;
        if (n < HH)          { Us = Uz; nn = n; }
        else if (n < 2 * HH) { Us = Ur; nn = n - HH; }
        else                 { Us = Uo; nn = n - 2 * HH; }
        #pragma unroll
        for (int j = 0; j < 8; ++j) {
            int k = k0 + j;
            v[j] = (k < DD) ? f2bf(Us[k * HH + nn]) : (short)0;
        }
        *(short8*)&Up[(long)idx * 8] = v;
    }
}

// ---------------------------------------------------------------------------
// Inter-workgroup epoch barrier (8-wg row-group). NO fences anywhere (r5's
// agent release/acquire fences lowered to buffer_wbl2/buffer_inv — full L2
// tag-walks, ~µs each, 4/step = the whole r5 runtime). Data AND counters move
// through the LLC via sc0sc1 (SYSTEM-scope) operations, so no cache
// maintenance is needed and correctness is independent of wg->XCD mapping:
// producer: sc-stores -> __syncthreads (vmcnt0: data at LLC) -> relaxed add.
// consumer: relaxed poll -> __syncthreads -> sc-loads.
// ---------------------------------------------------------------------------
static __device__ __forceinline__ void bar_arrive(int* c) {
    __syncthreads();                 // all wg's sc-stores complete (vmcnt 0)
    if (threadIdx.x == 0)
        __hip_atomic_fetch_add(c, 1, __ATOMIC_RELAXED, __HIP_MEMORY_SCOPE_SYSTEM);
}
static __device__ __forceinline__ void bar_wait(int* c, int tgt) {
    if (threadIdx.x == 0) {
        int it = 0;
        while (__hip_atomic_load(c, __ATOMIC_RELAXED, __HIP_MEMORY_SCOPE_SYSTEM) < tgt
               && it < 65536) { ++it; __builtin_amdgcn_s_sleep(1); }
    }
    __syncthreads();
}

// ---------------------------------------------------------------------------
// k_gru: 256 wgs (32 row-tiles x 8 col-groups) x 256 thr (4 waves), 1 wg/CU.
// XCD-swizzled (perf only; correctness is mapping-independent).
// Per wg: rows rt*16..+16, output col-slice cg*64..+64 of each gate.
// Resident: Wz/Wr col-slice in LDS (128KB, once); Uz/Ur/Uo/Wo frags in VGPRs
// (46 frags, once); h f32 + z in VGPRs (C/D layout).
// Exchange buffers hb_g/rh_g are COLUMN-major [rt][col512][row16] bf16 so a
// lane's 4 C/D values (1 col x 4 consecutive rows) are one 8B pack, moved
// with relaxed SYSTEM-scope atomics (sc0 sc1: bypass L1/L2, land in LLC).
// WAR-safety without double buffering: hb written at step t is re-written
// only after bar1(t+1) (which follows all phase-A reads of step t+1); rh
// symmetric via bar2.
// LDS: Wlds 128K | Ab 16K (hb/rh shared) | As 10K = 154 KiB
// ---------------------------------------------------------------------------
__global__ __launch_bounds__(256, 1) void k_gru(
    const int* __restrict__ tok1, const int* __restrict__ tok2,
    const float* __restrict__ emb,
    const short* __restrict__ Wzr_p, const short* __restrict__ Wo_p,
    const short* __restrict__ Up,
    const float* __restrict__ bz, const float* __restrict__ br,
    const float* __restrict__ bo,
    short* __restrict__ rh_g, short* __restrict__ hb_g,
    int* __restrict__ ctrs,
    float* __restrict__ h_final)
{
    extern __shared__ char smem[];
    short* Wlds = (short*)smem;              // [2][4fN][16kb][64][8] = 131072 B
    short* Ab   = (short*)(smem + 131072);   // [16][512] bf16 swz = 16384 B
    short* As   = (short*)(smem + 147456);   // [16][320] bf16 swz = 10240 B

    const int tid  = threadIdx.x;
    const int lane = tid & 63;
    const int w    = tid >> 6;               // wave 0..3
    const int r16  = lane & 15;
    const int kg   = lane >> 4;
    const int wg   = blockIdx.x;
    // XCD swizzle: round-robin dispatch puts wg on XCD wg%8; this mapping
    // gives row-group rt all 8 of its wgs on XCD rt>>2 (4 rgs/XCD = 32 CUs).
    const int rt   = (wg & 7) * 4 + ((wg >> 3) & 3);   // row-tile 0..31
    const int cg   = wg >> 5;                          // col-group 0..7
    const int ncol = cg * 64 + w * 16 + r16; // this lane's output column
    int* bar1 = ctrs + rt * 32;              // rh-ready
    int* bar2 = ctrs + rt * 32 + 16;         // h-ready
    ull* rh_x = (ull*)(rh_g + (size_t)rt * 8192);   // [col][rb] 8B units
    ull* hb_x = (ull*)(hb_g + (size_t)rt * 8192);

    // ---- one-time: Wz/Wr slice -> LDS (fragment-major, verbatim copy) ----
    {
        const f32x4* gz = (const f32x4*)(Wzr_p + (size_t)cg * 32768);
        const f32x4* gr = (const f32x4*)(Wzr_p + (size_t)(262144 + cg * 32768));
        f32x4* dz = (f32x4*)Wlds;
        f32x4* dr = (f32x4*)(Wlds + 32768);
        for (int i = tid; i < 4096; i += 256) { dz[i] = gz[i]; dr[i] = gr[i]; }
    }
    // ---- one-time: U/Wo fragments -> registers (static-indexed arrays) ----
    short8 fUz[10], fUr[10], fUo[10], fWo[16];
    {
        const short8* up = (const short8*)Up;
        const short8* wo = (const short8*)Wo_p;
        int fz = cg * 4 + w, fr = 32 + cg * 4 + w, fo = 64 + cg * 4 + w;
        #pragma unroll
        for (int kb = 0; kb < 10; ++kb) {
            fUz[kb] = up[(size_t)(fz * 10 + kb) * 64 + lane];
            fUr[kb] = up[(size_t)(fr * 10 + kb) * 64 + lane];
            fUo[kb] = up[(size_t)(fo * 10 + kb) * 64 + lane];
        }
        #pragma unroll
        for (int kb = 0; kb < 16; ++kb)
            fWo[kb] = wo[(size_t)((cg * 4 + w) * 16 + kb) * 64 + lane];
    }
    const float bzv = bz[ncol], brv = br[ncol], bov = bo[ncol];

    // ---- one-time: zero-pad As cols 300..319 (never restaged) ----
    for (int i = tid; i < 160; i += 256) {
        int row = i / 10, j = i % 10;
        *(int*)((char*)As + row * 640 + swz(row, 600 + j * 4)) = 0;
    }
    __syncthreads();

    // ---- stage As(t=0): 16 gathered emb rows, f32 -> bf16, swizzled ----
    {
        int row = tid >> 4, sgt = tid & 15;
        int m = rt * 16 + row;
        const int* tk = (m >= BB) ? tok2 : tok1;
        const float* er = emb + (size_t)tk[(m & 255) * TT + 0] * DD;
        #pragma unroll
        for (int p = 0; p < 5; ++p) {
            int c = sgt * 4 + p * 64;
            if (c < DD) {
                float4 v = *(const float4*)(er + c);
                s16x4 o;
                o[0] = f2bf(v.x); o[1] = f2bf(v.y); o[2] = f2bf(v.z); o[3] = f2bf(v.w);
                *(s16x4*)((char*)As + row * 640 + swz(row, c * 2)) = o;
            }
        }
    }
    __syncthreads();

    float hreg[4] = {0.f, 0.f, 0.f, 0.f};   // h[row=kg*4+q][ncol], f32 master
    float zreg[4];

    for (int t = 0; t < TT; ++t) {
        // ================= phase A =================
        f32x4 zac = {0,0,0,0}, rac = {0,0,0,0};
        #pragma unroll
        for (int kb = 0; kb < 10; ++kb) {    // x@U (h-independent: pre-wait)
            short8 au = *(const short8*)((char*)As + r16 * 640
                          + swz(r16, kb * 64 + kg * 16));
            zac = __builtin_amdgcn_mfma_f32_16x16x32_bf16(au, fUz[kb], zac, 0, 0, 0);
            rac = __builtin_amdgcn_mfma_f32_16x16x32_bf16(au, fUr[kb], rac, 0, 0, 0);
        }
        if (t > 0) {
            bar_wait(bar2, 8 * t);           // h(t-1) slices ready (at LLC)
            #pragma unroll
            for (int it = 0; it < 8; ++it) { // stage hb -> Ab (transpose)
                int u = tid + it * 256;      // 2048 x 8B: col=u>>2, rows (u&3)*4..+4
                ull v = __hip_atomic_load(hb_x + u, __ATOMIC_RELAXED,
                                          __HIP_MEMORY_SCOPE_SYSTEM);
                union { ull q; short s[4]; } uq; uq.q = v;
                int col = u >> 2, rb = u & 3;
                #pragma unroll
                for (int j = 0; j < 4; ++j) {
                    int row = rb * 4 + j;
                    *(short*)((char*)Ab + row * 1024 + swz(row, col * 2)) = uq.s[j];
                }
            }
            __syncthreads();
            #pragma unroll
            for (int kb = 0; kb < 16; ++kb) {          // h@[Wz|Wr]
                short8 ah = *(const short8*)((char*)Ab + r16 * 1024
                              + swz(r16, kb * 64 + kg * 16));
                short8 wzf = *(const short8*)&Wlds[(w * 16 + kb) * 512 + lane * 8];
                short8 wrf = *(const short8*)&Wlds[32768 + (w * 16 + kb) * 512 + lane * 8];
                zac = __builtin_amdgcn_mfma_f32_16x16x32_bf16(ah, wzf, zac, 0, 0, 0);
                rac = __builtin_amdgcn_mfma_f32_16x16x32_bf16(ah, wrf, rac, 0, 0, 0);
            }
        }
        // epilogue A: z local; rh (bf16, col-major 8B pack) -> LLC exchange
        #pragma unroll
        for (int q = 0; q < 4; ++q)
            zreg[q] = 1.f / (1.f + __expf(-(zac[q] + bzv)));
        if (t > 0) {
            union { ull q; short s[4]; } pk;
            #pragma unroll
            for (int q = 0; q < 4; ++q) {
                float rg = 1.f / (1.f + __expf(-(rac[q] + brv)));
                pk.s[q] = f2bf(rg * hreg[q]);
            }
            __hip_atomic_store(rh_x + (ncol * 4 + kg), pk.q,
                               __ATOMIC_RELAXED, __HIP_MEMORY_SCOPE_SYSTEM);
            bar_arrive(bar1);
        }

        // ================= phase B =================
        f32x4 oac = {0,0,0,0};
        #pragma unroll
        for (int kb = 0; kb < 10; ++kb) {    // x@Uo (pre-wait)
            short8 au = *(const short8*)((char*)As + r16 * 640
                          + swz(r16, kb * 64 + kg * 16));
            oac = __builtin_amdgcn_mfma_f32_16x16x32_bf16(au, fUo[kb], oac, 0, 0, 0);
        }
        __syncthreads();                     // all As(t) reads complete
        if (t < TT - 1) {                    // stage As(t+1) into wait shadow
            int row = tid >> 4, sgt = tid & 15;
            int m = rt * 16 + row;
            const int* tk = (m >= BB) ? tok2 : tok1;
            const float* er = emb + (size_t)tk[(m & 255) * TT + (t + 1)] * DD;
            #pragma unroll
            for (int p = 0; p < 5; ++p) {
                int c = sgt * 4 + p * 64;
                if (c < DD) {
                    float4 v = *(const float4*)(er + c);
                    s16x4 o;
                    o[0] = f2bf(v.x); o[1] = f2bf(v.y); o[2] = f2bf(v.z); o[3] = f2bf(v.w);
                    *(s16x4*)((char*)As + row * 640 + swz(row, c * 2)) = o;
                }
            }
        }
        if (t > 0) {
            bar_wait(bar1, 8 * t);           // rh(t) slices ready (at LLC)
            #pragma unroll
            for (int it = 0; it < 8; ++it) { // stage rh -> Ab (transpose)
                int u = tid + it * 256;
                ull v = __hip_atomic_load(rh_x + u, __ATOMIC_RELAXED,
                                          __HIP_MEMORY_SCOPE_SYSTEM);
                union { ull q; short s[4]; } uq; uq.q = v;
                int col = u >> 2, rb = u & 3;
                #pragma unroll
                for (int j = 0; j < 4; ++j) {
                    int row = rb * 4 + j;
                    *(short*)((char*)Ab + row * 1024 + swz(row, col * 2)) = uq.s[j];
                }
            }
            __syncthreads();
            #pragma unroll
            for (int kb = 0; kb < 16; ++kb) {          // rh@Wo
                short8 ar = *(const short8*)((char*)Ab + r16 * 1024
                              + swz(r16, kb * 64 + kg * 16));
                oac = __builtin_amdgcn_mfma_f32_16x16x32_bf16(ar, fWo[kb], oac, 0, 0, 0);
            }
        } else {
            __syncthreads();                 // As(1) visible (no bar1 at t=0)
        }
        // epilogue B: h' = z*h + (1-z)*tanh(.); f32 in reg, bf16 -> LLC
        {
            union { ull q; short s[4]; } pk;
            #pragma unroll
            for (int q = 0; q < 4; ++q) {
                float pre = oac[q] + bov;
                float e = __expf(2.f * pre);     // tanh, inf-safe
                float o = 1.f - 2.f / (e + 1.f);
                float hn = zreg[q] * hreg[q] + (1.f - zreg[q]) * o;
                hreg[q] = hn;
                pk.s[q] = f2bf(hn);
            }
            __hip_atomic_store(hb_x + (ncol * 4 + kg), pk.q,
                               __ATOMIC_RELAXED, __HIP_MEMORY_SCOPE_SYSTEM);
        }
        bar_arrive(bar2);
    }

    // ---- final h (f32) ----
    #pragma unroll
    for (int q = 0; q < 4; ++q)
        h_final[(size_t)(rt * 16 + kg * 4 + q) * HH + ncol] = hreg[q];
}

// ---------------------------------------------------------------------------
// Head: v = relu([h1, h2, (h1-h2)^2, h1*h2]);  out = v @ U + b.  grid 256.
// ---------------------------------------------------------------------------
__global__ __launch_bounds__(256) void k_head(
    const float* __restrict__ h, const float* __restrict__ U,
    const float* __restrict__ bias, float* __restrict__ out)
{
    const int b = blockIdx.x, tid = threadIdx.x;
    const float* h1 = h + b * HH;
    const float* h2 = h + (BB + b) * HH;
    float a0 = 0.f, a1 = 0.f;
    #pragma unroll
    for (int l = 0; l < 8; ++l) {
        int i = tid + l * 256;        // [0,2048)
        int seg = i >> 9, off = i & 511;
        float v;
        if (seg == 0)      v = fmaxf(h1[off], 0.f);
        else if (seg == 1) v = fmaxf(h2[off], 0.f);
        else if (seg == 2) { float d = h1[off] - h2[off]; v = d * d; }
        else               v = fmaxf(h1[off] * h2[off], 0.f);
        a0 += v * U[i * 2];
        a1 += v * U[i * 2 + 1];
    }
    __shared__ float red0[256];
    __shared__ float red1[256];
    red0[tid] = a0; red1[tid] = a1;
    __syncthreads();
    for (int sft = 128; sft > 0; sft >>= 1) {
        if (tid < sft) { red0[tid] += red0[tid + sft]; red1[tid] += red1[tid + sft]; }
        __syncthreads();
    }
    if (tid == 0) {
        out[b * 2]     = red0[0] + bias[0];
        out[b * 2 + 1] = red1[0] + bias[1];
    }
}

// ---------------------------------------------------------------------------
extern "C" void kernel_launch(void* const* d_in, const int* in_sizes, int n_in,
                              void* d_out, int out_size, void* d_ws, size_t ws_size,
                              hipStream_t stream)
{
    (void)in_sizes; (void)n_in; (void)out_size; (void)ws_size;
    const int*   tok1 = (const int*)  d_in[0];
    const int*   tok2 = (const int*)  d_in[1];
    const float* emb  = (const float*)d_in[2];
    const float* Uz   = (const float*)d_in[3];
    const float* Ur   = (const float*)d_in[4];
    const float* Uo   = (const float*)d_in[5];
    const float* Wz   = (const float*)d_in[6];
    const float* Wr   = (const float*)d_in[7];
    const float* Wo   = (const float*)d_in[8];
    const float* bz   = (const float*)d_in[9];
    const float* br   = (const float*)d_in[10];
    const float* bo   = (const float*)d_in[11];
    const float* U    = (const float*)d_in[12];
    const float* bb   = (const float*)d_in[13];
    float* out = (float*)d_out;

    // ws: Wzr_p 1MB | Wo_p 0.5MB | Up 0.96MB | rh_g 0.5MB | hb_g 0.5MB |
    //     h_final 1MB | ctrs 4KB   (total ~4.5MB)
    char* ws = (char*)d_ws;
    short* Wzr_p   = (short*)ws;
    short* Wo_p    = Wzr_p + 524288;
    short* Up      = Wo_p + 262144;
    short* rh_g    = Up + 491520;
    short* hb_g    = rh_g + 262144;
    float* h_final = (float*)(hb_g + 262144);
    int*   ctrs    = (int*)(h_final + 262144);

    static bool attr_set = false;
    if (!attr_set) {
        (void)hipFuncSetAttribute((const void*)k_gru,
                                  hipFuncAttributeMaxDynamicSharedMemorySize, 157696);
        attr_set = true;
    }

    hipMemsetAsync(ctrs, 0, 32 * 32 * sizeof(int), stream);
    dim3 blk(256);
    k_pack<<<dim3(624), blk, 0, stream>>>(Wz, Wr, Wo, Uz, Ur, Uo, Wzr_p, Wo_p, Up);
    k_gru<<<dim3(256), blk, 157696, stream>>>(
        tok1, tok2, emb, Wzr_p, Wo_p, Up, bz, br, bo, rh_g, hb_g, ctrs, h_final);
    k_head<<<dim3(256), blk, 0, stream>>>(h_final, U, bb, out);
}